// Round 10
// baseline (281.554 us; speedup 1.0000x reference)
//
#include <hip/hip_runtime.h>
#include <math.h>

#define B_   64
#define N_   197
#define C_   768
#define H_   12
#define D_   64
#define BN   12608      // B_*N_
#define BN_PAD 12672    // 99*128 (GEMM M padded)
#define QKV_ELEMS 9682944   // B_*H_*N_*D_ = BN*C_
#define SCALE 0.125f    // D^-0.5
#define STRV 80         // Vt/Ps LDS row stride (ushorts): 160B, 16B-aligned
#define TPAD 72         // T4 bias row pad (ushorts): 144B rows, 16B-aligned

typedef unsigned short ushort_t;
using bf16x8  = __attribute__((ext_vector_type(8))) __bf16;
using floatx4 = __attribute__((ext_vector_type(4))) float;
using ushort8 = __attribute__((ext_vector_type(8))) unsigned short;

__device__ __forceinline__ ushort_t f2bf(float f) {
    union { float f; unsigned u; } v; v.f = f;
    unsigned r = v.u + 0x7FFF + ((v.u >> 16) & 1);   // RNE
    return (ushort_t)(r >> 16);
}

__device__ __forceinline__ float bf2f(ushort_t u) {
    union { unsigned u; float f; } v; v.u = ((unsigned)u) << 16;
    return v.f;
}

__device__ __forceinline__ void gload_lds16(const void* g, void* l) {
    __builtin_amdgcn_global_load_lds(
        (const __attribute__((address_space(1))) unsigned*)g,
        (__attribute__((address_space(3))) unsigned*)l, 16, 0, 0);
}

// T1: bijective XCD-chunked block remap (m204).
__device__ __forceinline__ int xcd_chunk(int orig, int nwg) {
    const int q = nwg >> 3, r = nwg & 7;
    const int x = orig & 7, i = orig >> 3;
    const int base = (x < r) ? x * (q + 1) : r * (q + 1) + (x - r) * q;
    return base + i;
}

// ---------------------------------------------------------------------------
// fused fp32 -> bf16 conversion for all three tensors (one launch, R4-proven)
// ranges (float4 units): x 2420736 | qkv_w 442368 | proj_w 147456
// total 3010560 = 11760 * 256 exactly.
// ---------------------------------------------------------------------------
__global__ __launch_bounds__(256) void cvt_all(
    const float* __restrict__ x,  const float* __restrict__ w1,
    const float* __restrict__ w2,
    ushort_t* __restrict__ xb, ushort_t* __restrict__ wb,
    ushort_t* __restrict__ pwb)
{
    const int i = blockIdx.x * 256 + threadIdx.x;
    const float* s; ushort_t* d; int j;
    if (i < 2420736)      { s = x;  d = xb;  j = i; }
    else if (i < 2863104) { s = w1; d = wb;  j = i - 2420736; }
    else                  { s = w2; d = pwb; j = i - 2863104; }
    float4 v = ((const float4*)s)[j];
    ushort4 o;
    o.x = f2bf(v.x); o.y = f2bf(v.y); o.z = f2bf(v.z); o.w = f2bf(v.w);
    ((ushort4*)d)[j] = o;
}

// ---------------------------------------------------------------------------
// build_rpb: pregather relative-position bias, TRANSPOSED + rt-partitioned:
//   T4[rt][h][m][n_loc] (bf16), n = rt*64 + n_loc, n_loc in [0,72).
// Row = 72 ushorts = 144B (16B-aligned) so an attn block's per-cc slice
// (m = cc*64..cc*64+63, all n_loc) is ONE contiguous 9216B slab -> staged to
// LDS by 9 global_load_lds calls.  Invalid (n>196) entries = 0 (rows are
// discarded by the attn epilogue).  Lives in the dead wb region (built AFTER
// qkv_gemm).  idx math identical to gen_relative_position_index.
// ---------------------------------------------------------------------------
__global__ __launch_bounds__(256) void build_rpb(
    const float* __restrict__ rel_table,  // [732, 12]
    ushort_t* __restrict__ t4)            // [4][12][197][72] bf16
{
    const int p = blockIdx.x * 256 + threadIdx.x;   // over 4*197*72 = 56736
    if (p >= 4 * 197 * TPAD) return;
    const int nl = p % TPAD;
    const int rest = p / TPAD;
    const int m = rest % 197, rt = rest / 197;
    const int n = rt * 64 + nl;
    const bool valid = (n < 197);
    int idx = 0;
    if (valid) {
        if (n == 0 && m == 0)      idx = 731;
        else if (n == 0)           idx = 729;
        else if (m == 0)           idx = 730;
        else {
            const int pp = n - 1, qq = m - 1;
            idx = (pp / 14 - qq / 14 + 13) * 27 + (pp % 14 - qq % 14 + 13);
        }
    }
#pragma unroll
    for (int h = 0; h < 12; ++h)
        t4[((size_t)(rt * 12 + h) * 197 + m) * TPAD + nl] =
            valid ? f2bf(rel_table[idx * 12 + h]) : (ushort_t)0;
}

// ---------------------------------------------------------------------------
// Kernel 1: QKV projection GEMM (R0 128^2 core + XCD-chunked remap).
// R10 delta: __launch_bounds__(256,5) — LDS 32KB x 5 = 160KB exactly; 60
// VGPRs easily fit 20 waves/CU.  More co-resident blocks hide the per-K-tile
// vmcnt(0)+barrier drain (the known 2-phase bottleneck).
// Epilogue writes bf16 Q(scaled)/K/V in (B,H,N,D).
// ---------------------------------------------------------------------------
__global__ __launch_bounds__(256, 5) void qkv_gemm_mfma(
    const ushort_t* __restrict__ xb,   // [BN_PAD, 768] bf16
    const ushort_t* __restrict__ wb,   // [2304, 768] bf16
    const float* __restrict__ qb,
    const float* __restrict__ kb,
    const float* __restrict__ vb,
    ushort_t* __restrict__ qkvb)       // 3 x [B,H,N,D] bf16
{
    __shared__ ushort_t lA[128 * 64];
    __shared__ ushort_t lB[128 * 64];
    const int t = threadIdx.x;
    const int w = t >> 6, lane = t & 63;
    const int quad = lane >> 4, li = lane & 15;
    const int wm = w >> 1, wn = w & 1;
    const int f = xcd_chunk(blockIdx.y * 18 + blockIdx.x, 18 * 99);
    const int o0 = (f % 18) * 128, m0 = (f / 18) * 128;

    floatx4 acc[4][4];
#pragma unroll
    for (int i = 0; i < 4; ++i)
#pragma unroll
        for (int j = 0; j < 4; ++j) acc[i][j] = (floatx4)0.f;

    const int rloc = lane >> 3;            // row within 8-row DMA chunk
    const int gdma = (lane & 7) ^ rloc;    // swizzled global granule
    const int rx   = li & 7;               // frag-read un-swizzle key

    for (int kt = 0; kt < 12; ++kt) {
        const int k0 = kt * 64;
#pragma unroll
        for (int s = 0; s < 4; ++s) {
            const int rb = w * 32 + s * 8;
            gload_lds16(xb + ((size_t)(m0 + rb + rloc)) * 768 + k0 + gdma * 8,
                        &lA[rb * 64]);
            gload_lds16(wb + ((size_t)(o0 + rb + rloc)) * 768 + k0 + gdma * 8,
                        &lB[rb * 64]);
        }
        __syncthreads();
#pragma unroll
        for (int kk = 0; kk < 2; ++kk) {
            bf16x8 af[4], bfr[4];
#pragma unroll
            for (int mi = 0; mi < 4; ++mi)
                af[mi] = *(const bf16x8*)
                    &lA[(wm * 64 + mi * 16 + li) * 64 + ((kk * 4 + quad) ^ rx) * 8];
#pragma unroll
            for (int ni = 0; ni < 4; ++ni)
                bfr[ni] = *(const bf16x8*)
                    &lB[(wn * 64 + ni * 16 + li) * 64 + ((kk * 4 + quad) ^ rx) * 8];
#pragma unroll
            for (int mi = 0; mi < 4; ++mi)
#pragma unroll
                for (int ni = 0; ni < 4; ++ni)
                    acc[mi][ni] = __builtin_amdgcn_mfma_f32_16x16x32_bf16(
                        af[mi], bfr[ni], acc[mi][ni], 0, 0, 0);
        }
        __syncthreads();
    }

    const int which = o0 / 768;
    const float* bias = (which == 0) ? qb : ((which == 1) ? kb : vb);
    ushort_t* dst = qkvb + (size_t)which * QKV_ELEMS;
    const float sc = (which == 0) ? SCALE : 1.0f;

#pragma unroll
    for (int mi = 0; mi < 4; ++mi) {
#pragma unroll
        for (int r = 0; r < 4; ++r) {
            const int m = m0 + wm * 64 + mi * 16 + quad * 4 + r;
            if (m < BN) {
                const int b = m / 197, n = m % 197;
#pragma unroll
                for (int ni = 0; ni < 4; ++ni) {
                    const int o  = o0 + wn * 64 + ni * 16 + li;
                    const int ol = o - which * 768;
                    const int h = ol >> 6, d = ol & 63;
                    dst[(((size_t)b * 12 + h) * 197 + n) * 64 + d] =
                        f2bf((acc[mi][ni][r] + bias[ol]) * sc);
                }
            }
        }
    }
}

// ---------------------------------------------------------------------------
// Kernel 2: fused MFMA attention (R9-proven: single-pass softmax, merged
// QsPs buffer, 5 blocks/CU, setprio around MFMA clusters).  Unchanged.
// ---------------------------------------------------------------------------
__global__ __launch_bounds__(256, 5) void attn_mfma(
    const ushort_t* __restrict__ qkvb,    // Qb,Kb,Vb consecutive, bf16
    const ushort_t* __restrict__ t4,      // [4][12][197][72] bf16
    ushort_t* __restrict__ aout)          // [BN, 768] bf16
{
    __shared__ ushort_t QsPs[64 * STRV];  // Q stage -> bias tile -> Ps
    __shared__ ushort_t Ks[64 * 64];
    __shared__ ushort_t Vt[64 * STRV];

    const int f = xcd_chunk(blockIdx.y * 4 + blockIdx.x, 4 * 768);
    const int rt = f & 3, bh = f >> 2;
    const int h = bh % 12, bb = bh / 12;
    const int t = threadIdx.x;
    const int w = t >> 6, lane = t & 63, quad = lane >> 4, li = lane & 15;
    const size_t base = (size_t)bh * (197 * 64);
    const ushort_t* Qg = qkvb + base;
    const ushort_t* Kg = qkvb + (size_t)QKV_ELEMS + base;
    const ushort_t* Vg = qkvb + (size_t)2 * QKV_ELEMS + base;
    const int r0 = rt * 64;
    const ushort_t* slab = t4 + (size_t)(rt * 12 + h) * (197 * TPAD);

    {
        const int rloc = lane >> 3, g = (lane & 7) ^ rloc;
#pragma unroll
        for (int s = 0; s < 2; ++s) {
            const int rb = (w * 2 + s) * 8;
            gload_lds16(Qg + (size_t)(r0 + rb + rloc) * 64 + g * 8, &QsPs[rb * 64]);
        }
    }

    int nrow[4];
#pragma unroll
    for (int r = 0; r < 4; ++r) nrow[r] = r0 + w * 16 + quad * 4 + r;

    __syncthreads();

    bf16x8 aq0, aq1;
    {
        const int rq = w * 16 + li, rxq = rq & 7;
        aq0 = *(const bf16x8*)&QsPs[rq * 64 + (quad ^ rxq) * 8];
        aq1 = *(const bf16x8*)&QsPs[rq * 64 + ((4 + quad) ^ rxq) * 8];
    }
    // Workgroup barrier: all waves' Q-frag ds_reads retired before any wave
    // DMAs the first bias tile into QsPs (R6's race lesson).
    __syncthreads();

    // ---- Phase 1: QK^T + bias, all score tiles in registers -------------
    floatx4 sv[13];    // idx = cc*4+tl (cc<3) ; 12 = (cc=3, tl=0)
#pragma unroll
    for (int cc = 0; cc < 4; ++cc) {
        {
            const int rloc = lane >> 3, g = (lane & 7) ^ rloc;
#pragma unroll
            for (int s = 0; s < 2; ++s) {
                const int rb = (w * 2 + s) * 8;
                if (cc < 3 || rb < 16)   // cc=3: only K rows 0..15 needed
                    gload_lds16(Kg + (size_t)(cc * 64 + rb + rloc) * 64 + g * 8,
                                &Ks[rb * 64]);
            }
        }
        // bias tile: 9216B contiguous (cc=3: first 3 chunks cover rows 0..21)
        for (int c = w; c < ((cc == 3) ? 3 : 9); c += 4)
            gload_lds16(slab + (size_t)cc * 4608 + c * 512 + lane * 8,
                        &QsPs[c * 512]);
        __syncthreads();

        __builtin_amdgcn_s_setprio(1);
#pragma unroll
        for (int tl = 0; tl < 4; ++tl) {
            if (cc < 3 || tl == 0) {
                const int rk = tl * 16 + li, rxk = rk & 7;
                bf16x8 bk0 = *(const bf16x8*)&Ks[rk * 64 + (quad ^ rxk) * 8];
                bf16x8 bk1 = *(const bf16x8*)&Ks[rk * 64 + ((4 + quad) ^ rxk) * 8];
                floatx4 sa = (floatx4)0.f;
                sa = __builtin_amdgcn_mfma_f32_16x16x32_bf16(aq0, bk0, sa, 0, 0, 0);
                sa = __builtin_amdgcn_mfma_f32_16x16x32_bf16(aq1, bk1, sa, 0, 0, 0);
                const int mg = cc * 64 + tl * 16 + li;
                if (mg >= 197) {
#pragma unroll
                    for (int r = 0; r < 4; ++r) sa[r] = -INFINITY;
                } else {
                    ushort4 bv = *(const ushort4*)
                        &QsPs[(tl * 16 + li) * TPAD + w * 16 + quad * 4];
                    sa[0] += bf2f(bv.x);
                    sa[1] += bf2f(bv.y);
                    sa[2] += bf2f(bv.z);
                    sa[3] += bf2f(bv.w);
                }
                sv[cc * 4 + tl] = sa;    // static index (loops unrolled)
            }
        }
        __builtin_amdgcn_s_setprio(0);
        __syncthreads();
    }

    // ---- Phase 2: single-pass softmax (registers only) ------------------
    float inv[4];
#pragma unroll
    for (int r = 0; r < 4; ++r) {
        float mx = sv[0][r];
#pragma unroll
        for (int i = 1; i < 13; ++i) mx = fmaxf(mx, sv[i][r]);
        mx = fmaxf(mx, __shfl_xor(mx, 1));
        mx = fmaxf(mx, __shfl_xor(mx, 2));
        mx = fmaxf(mx, __shfl_xor(mx, 4));
        mx = fmaxf(mx, __shfl_xor(mx, 8));
        float rs = 0.f;
#pragma unroll
        for (int i = 0; i < 13; ++i) {
            const float p = __expf(sv[i][r] - mx);   // -INF -> 0
            sv[i][r] = p;
            rs += p;
        }
        rs += __shfl_xor(rs, 1);
        rs += __shfl_xor(rs, 2);
        rs += __shfl_xor(rs, 4);
        rs += __shfl_xor(rs, 8);
        inv[r] = 1.0f / rs;
    }

    floatx4 accO[4];
#pragma unroll
    for (int dt = 0; dt < 4; ++dt) accO[dt] = (floatx4)0.f;

    // ---- Phase 3: PV (Ps lives in the QsPs buffer; bias tile is dead) ----
#pragma unroll
    for (int cc = 0; cc < 4; ++cc) {
        {
            const int c = lane;
            const int mg = cc * 64 + c;
            ushort8 v0, v1;
            if (mg < 197) {
                v0 = *(const ushort8*)(Vg + (size_t)mg * 64 + w * 16);
                v1 = *(const ushort8*)(Vg + (size_t)mg * 64 + w * 16 + 8);
            } else {
                v0 = (ushort8)(unsigned short)0; v1 = v0;
            }
#pragma unroll
            for (int j = 0; j < 8; ++j) Vt[(w * 16 + j) * STRV + c] = v0[j];
#pragma unroll
            for (int j = 0; j < 8; ++j) Vt[(w * 16 + 8 + j) * STRV + c] = v1[j];
        }
        // write P tile from registers (cc=3: only tl=0; stale cols x V=0)
#pragma unroll
        for (int r = 0; r < 4; ++r) {
            const int prow = w * 16 + quad * 4 + r;
#pragma unroll
            for (int tl = 0; tl < 4; ++tl)
                if (cc < 3 || tl == 0)
                    QsPs[prow * STRV + tl * 16 + li] = f2bf(sv[cc * 4 + tl][r]);
        }
        __syncthreads();

        {
            const int rp = w * 16 + li;
            bf16x8 pa0 = *(const bf16x8*)&QsPs[rp * STRV + 0  + quad * 8];
            bf16x8 pa1 = *(const bf16x8*)&QsPs[rp * STRV + 32 + quad * 8];
            __builtin_amdgcn_s_setprio(1);
#pragma unroll
            for (int dt = 0; dt < 4; ++dt) {
                const int rv = dt * 16 + li;
                bf16x8 bv0 = *(const bf16x8*)&Vt[rv * STRV + 0  + quad * 8];
                bf16x8 bv1 = *(const bf16x8*)&Vt[rv * STRV + 32 + quad * 8];
                accO[dt] = __builtin_amdgcn_mfma_f32_16x16x32_bf16(
                    pa0, bv0, accO[dt], 0, 0, 0);
                accO[dt] = __builtin_amdgcn_mfma_f32_16x16x32_bf16(
                    pa1, bv1, accO[dt], 0, 0, 0);
            }
            __builtin_amdgcn_s_setprio(0);
        }
        __syncthreads();
    }

#pragma unroll
    for (int r = 0; r < 4; ++r) {
        const int n = nrow[r];
        if (n < 197) {
            ushort_t* op = aout + ((size_t)(bb * 197 + n)) * 768 + h * 64;
#pragma unroll
            for (int dt = 0; dt < 4; ++dt)
                op[dt * 16 + li] = f2bf(accO[dt][r] * inv[r]);
        }
    }
}

// ---------------------------------------------------------------------------
// Kernel 3: output projection GEMM (R0 128^2 core + XCD-chunked remap).
// R10: __launch_bounds__(256,5) (same rationale as qkv).
// ---------------------------------------------------------------------------
__global__ __launch_bounds__(256, 5) void proj_gemm_mfma(
    const ushort_t* __restrict__ ab,   // [BN_PAD, 768] bf16
    const ushort_t* __restrict__ wb,   // [768, 768] bf16
    const float* __restrict__ bias,    // [768]
    float* __restrict__ out)           // [BN, 768] fp32
{
    __shared__ ushort_t lA[128 * 64];
    __shared__ ushort_t lB[128 * 64];
    const int t = threadIdx.x;
    const int w = t >> 6, lane = t & 63;
    const int quad = lane >> 4, li = lane & 15;
    const int wm = w >> 1, wn = w & 1;
    const int f = xcd_chunk(blockIdx.y * 6 + blockIdx.x, 6 * 99);
    const int o0 = (f % 6) * 128, m0 = (f / 6) * 128;

    floatx4 acc[4][4];
#pragma unroll
    for (int i = 0; i < 4; ++i)
#pragma unroll
        for (int j = 0; j < 4; ++j) acc[i][j] = (floatx4)0.f;

    const int rloc = lane >> 3;
    const int gdma = (lane & 7) ^ rloc;
    const int rx   = li & 7;

    for (int kt = 0; kt < 12; ++kt) {
        const int k0 = kt * 64;
#pragma unroll
        for (int s = 0; s < 4; ++s) {
            const int rb = w * 32 + s * 8;
            gload_lds16(ab + ((size_t)(m0 + rb + rloc)) * 768 + k0 + gdma * 8,
                        &lA[rb * 64]);
            gload_lds16(wb + ((size_t)(o0 + rb + rloc)) * 768 + k0 + gdma * 8,
                        &lB[rb * 64]);
        }
        __syncthreads();
#pragma unroll
        for (int kk = 0; kk < 2; ++kk) {
            bf16x8 af[4], bfr[4];
#pragma unroll
            for (int mi = 0; mi < 4; ++mi)
                af[mi] = *(const bf16x8*)
                    &lA[(wm * 64 + mi * 16 + li) * 64 + ((kk * 4 + quad) ^ rx) * 8];
#pragma unroll
            for (int ni = 0; ni < 4; ++ni)
                bfr[ni] = *(const bf16x8*)
                    &lB[(wn * 64 + ni * 16 + li) * 64 + ((kk * 4 + quad) ^ rx) * 8];
#pragma unroll
            for (int mi = 0; mi < 4; ++mi)
#pragma unroll
                for (int ni = 0; ni < 4; ++ni)
                    acc[mi][ni] = __builtin_amdgcn_mfma_f32_16x16x32_bf16(
                        af[mi], bfr[ni], acc[mi][ni], 0, 0, 0);
        }
        __syncthreads();
    }

#pragma unroll
    for (int mi = 0; mi < 4; ++mi) {
#pragma unroll
        for (int r = 0; r < 4; ++r) {
            const int m = m0 + wm * 64 + mi * 16 + quad * 4 + r;
            if (m < BN) {
                float* op = out + (size_t)m * 768;
#pragma unroll
                for (int ni = 0; ni < 4; ++ni) {
                    const int o = o0 + wn * 64 + ni * 16 + li;
                    op[o] = acc[mi][ni][r] + bias[o];
                }
            }
        }
    }
}

// ---------------------------------------------------------------------------
// ws layout (bytes):
//   [0, 58097664)            qkvb bf16 (3 x B,H,N,D)
//   [58097664, 77561856)     xb bf16 [12672 x 768]; aliased by aout bf16
//   [77561856, 81100800)     wb bf16 [2304 x 768] (live cvt..qkv), THEN
//                            T4 bias table [4][12][197][72] bf16 (1361664B,
//                            built after qkv, read by attn)
//   [81100800, 82280448)     pwb bf16 [768 x 768]
// ---------------------------------------------------------------------------
extern "C" void kernel_launch(void* const* d_in, const int* in_sizes, int n_in,
                              void* d_out, int out_size, void* d_ws, size_t ws_size,
                              hipStream_t stream)
{
    const float* x         = (const float*)d_in[0];
    const float* qkv_w     = (const float*)d_in[1];
    const float* q_bias    = (const float*)d_in[2];
    const float* k_bias    = (const float*)d_in[3];
    const float* v_bias    = (const float*)d_in[4];
    const float* rel_table = (const float*)d_in[5];
    const float* proj_w    = (const float*)d_in[6];
    const float* proj_b    = (const float*)d_in[7];
    float* out = (float*)d_out;

    char* ws = (char*)d_ws;
    ushort_t* qkvb  = (ushort_t*)ws;
    ushort_t* xb    = (ushort_t*)(ws + 58097664);
    ushort_t* aoutb = xb;                      // alias (xb dead after qkv_gemm)
    ushort_t* wb    = (ushort_t*)(ws + 77561856);
    ushort_t* t4b   = wb;                      // alias (wb dead after qkv_gemm)
    ushort_t* pwb   = (ushort_t*)(ws + 81100800);

    // one fused conversion launch: 3010560 float4's exactly = 11760 * 256
    cvt_all<<<11760, 256, 0, stream>>>(x, qkv_w, proj_w, xb, wb, pwb);

    dim3 g1(18, 99);
    qkv_gemm_mfma<<<g1, 256, 0, stream>>>(xb, wb, q_bias, k_bias, v_bias, qkvb);

    // T4 bias table into the now-dead wb region: 56736 threads = 222 * 256
    build_rpb<<<222, 256, 0, stream>>>(rel_table, t4b);

    dim3 g2(4, 768);
    attn_mfma<<<g2, 256, 0, stream>>>(qkvb, t4b, aoutb);

    dim3 g3(6, 99);
    proj_gemm_mfma<<<g3, 256, 0, stream>>>(aoutb, pwb, proj_b, out);
}

// Round 11
// 220.102 us; speedup vs baseline: 1.2792x; 1.2792x over previous
//
#include <hip/hip_runtime.h>
#include <math.h>

#define B_   64
#define N_   197
#define C_   768
#define H_   12
#define D_   64
#define BN   12608      // B_*N_
#define BN_PAD 12672    // 99*128 (GEMM M padded)
#define QKV_ELEMS 9682944   // B_*H_*N_*D_ = BN*C_
#define SCALE 0.125f    // D^-0.5
#define STRV 80         // Vt/Ps LDS row stride (ushorts): 160B, 16B-aligned
#define TPAD 72         // T4 bias row pad (ushorts): 144B rows, 16B-aligned

typedef unsigned short ushort_t;
using bf16x8  = __attribute__((ext_vector_type(8))) __bf16;
using floatx4 = __attribute__((ext_vector_type(4))) float;
using ushort8 = __attribute__((ext_vector_type(8))) unsigned short;

__device__ __forceinline__ ushort_t f2bf(float f) {
    union { float f; unsigned u; } v; v.f = f;
    unsigned r = v.u + 0x7FFF + ((v.u >> 16) & 1);   // RNE
    return (ushort_t)(r >> 16);
}

__device__ __forceinline__ float bf2f(ushort_t u) {
    union { unsigned u; float f; } v; v.u = ((unsigned)u) << 16;
    return v.f;
}

__device__ __forceinline__ void gload_lds16(const void* g, void* l) {
    __builtin_amdgcn_global_load_lds(
        (const __attribute__((address_space(1))) unsigned*)g,
        (__attribute__((address_space(3))) unsigned*)l, 16, 0, 0);
}

// T1: bijective XCD-chunked block remap (m204).
__device__ __forceinline__ int xcd_chunk(int orig, int nwg) {
    const int q = nwg >> 3, r = nwg & 7;
    const int x = orig & 7, i = orig >> 3;
    const int base = (x < r) ? x * (q + 1) : r * (q + 1) + (x - r) * q;
    return base + i;
}

// ---------------------------------------------------------------------------
// fused fp32 -> bf16 conversion for all three tensors (one launch, R4-proven)
// ranges (float4 units): x 2420736 | qkv_w 442368 | proj_w 147456
// total 3010560 = 11760 * 256 exactly.
// ---------------------------------------------------------------------------
__global__ __launch_bounds__(256) void cvt_all(
    const float* __restrict__ x,  const float* __restrict__ w1,
    const float* __restrict__ w2,
    ushort_t* __restrict__ xb, ushort_t* __restrict__ wb,
    ushort_t* __restrict__ pwb)
{
    const int i = blockIdx.x * 256 + threadIdx.x;
    const float* s; ushort_t* d; int j;
    if (i < 2420736)      { s = x;  d = xb;  j = i; }
    else if (i < 2863104) { s = w1; d = wb;  j = i - 2420736; }
    else                  { s = w2; d = pwb; j = i - 2863104; }
    float4 v = ((const float4*)s)[j];
    ushort4 o;
    o.x = f2bf(v.x); o.y = f2bf(v.y); o.z = f2bf(v.z); o.w = f2bf(v.w);
    ((ushort4*)d)[j] = o;
}

// ---------------------------------------------------------------------------
// build_rpb: pregather relative-position bias, TRANSPOSED + rt-partitioned:
//   T4[rt][h][m][n_loc] (bf16), n = rt*64 + n_loc, n_loc in [0,72).
// Row = 72 ushorts = 144B (16B-aligned) so an attn block's per-cc slice
// (m = cc*64..cc*64+63, all n_loc) is ONE contiguous 9216B slab -> staged to
// LDS by 9 global_load_lds calls.  Invalid (n>196) entries = 0 (rows are
// discarded by the attn epilogue).  Lives in the dead wb region (built AFTER
// qkv_gemm).  idx math identical to gen_relative_position_index.
// ---------------------------------------------------------------------------
__global__ __launch_bounds__(256) void build_rpb(
    const float* __restrict__ rel_table,  // [732, 12]
    ushort_t* __restrict__ t4)            // [4][12][197][72] bf16
{
    const int p = blockIdx.x * 256 + threadIdx.x;   // over 4*197*72 = 56736
    if (p >= 4 * 197 * TPAD) return;
    const int nl = p % TPAD;
    const int rest = p / TPAD;
    const int m = rest % 197, rt = rest / 197;
    const int n = rt * 64 + nl;
    const bool valid = (n < 197);
    int idx = 0;
    if (valid) {
        if (n == 0 && m == 0)      idx = 731;
        else if (n == 0)           idx = 729;
        else if (m == 0)           idx = 730;
        else {
            const int pp = n - 1, qq = m - 1;
            idx = (pp / 14 - qq / 14 + 13) * 27 + (pp % 14 - qq % 14 + 13);
        }
    }
#pragma unroll
    for (int h = 0; h < 12; ++h)
        t4[((size_t)(rt * 12 + h) * 197 + m) * TPAD + nl] =
            valid ? f2bf(rel_table[idx * 12 + h]) : (ushort_t)0;
}

// ---------------------------------------------------------------------------
// Kernel 1: QKV projection GEMM (R0 128^2 core + XCD-chunked remap).
// __launch_bounds__(256,4): VGPR cap 128 >= the 64-VGPR accumulator floor.
// R10's (256,5) capped VGPR at 48 -> acc spilled to scratch (WRITE_SIZE
// 56.7->94MB, dur 57->112us).  DO NOT raise the min-waves bound here.
// Epilogue writes bf16 Q(scaled)/K/V in (B,H,N,D).
// ---------------------------------------------------------------------------
__global__ __launch_bounds__(256, 4) void qkv_gemm_mfma(
    const ushort_t* __restrict__ xb,   // [BN_PAD, 768] bf16
    const ushort_t* __restrict__ wb,   // [2304, 768] bf16
    const float* __restrict__ qb,
    const float* __restrict__ kb,
    const float* __restrict__ vb,
    ushort_t* __restrict__ qkvb)       // 3 x [B,H,N,D] bf16
{
    __shared__ ushort_t lA[128 * 64];
    __shared__ ushort_t lB[128 * 64];
    const int t = threadIdx.x;
    const int w = t >> 6, lane = t & 63;
    const int quad = lane >> 4, li = lane & 15;
    const int wm = w >> 1, wn = w & 1;
    const int f = xcd_chunk(blockIdx.y * 18 + blockIdx.x, 18 * 99);
    const int o0 = (f % 18) * 128, m0 = (f / 18) * 128;

    floatx4 acc[4][4];
#pragma unroll
    for (int i = 0; i < 4; ++i)
#pragma unroll
        for (int j = 0; j < 4; ++j) acc[i][j] = (floatx4)0.f;

    const int rloc = lane >> 3;            // row within 8-row DMA chunk
    const int gdma = (lane & 7) ^ rloc;    // swizzled global granule
    const int rx   = li & 7;               // frag-read un-swizzle key

    for (int kt = 0; kt < 12; ++kt) {
        const int k0 = kt * 64;
#pragma unroll
        for (int s = 0; s < 4; ++s) {
            const int rb = w * 32 + s * 8;
            gload_lds16(xb + ((size_t)(m0 + rb + rloc)) * 768 + k0 + gdma * 8,
                        &lA[rb * 64]);
            gload_lds16(wb + ((size_t)(o0 + rb + rloc)) * 768 + k0 + gdma * 8,
                        &lB[rb * 64]);
        }
        __syncthreads();
#pragma unroll
        for (int kk = 0; kk < 2; ++kk) {
            bf16x8 af[4], bfr[4];
#pragma unroll
            for (int mi = 0; mi < 4; ++mi)
                af[mi] = *(const bf16x8*)
                    &lA[(wm * 64 + mi * 16 + li) * 64 + ((kk * 4 + quad) ^ rx) * 8];
#pragma unroll
            for (int ni = 0; ni < 4; ++ni)
                bfr[ni] = *(const bf16x8*)
                    &lB[(wn * 64 + ni * 16 + li) * 64 + ((kk * 4 + quad) ^ rx) * 8];
#pragma unroll
            for (int mi = 0; mi < 4; ++mi)
#pragma unroll
                for (int ni = 0; ni < 4; ++ni)
                    acc[mi][ni] = __builtin_amdgcn_mfma_f32_16x16x32_bf16(
                        af[mi], bfr[ni], acc[mi][ni], 0, 0, 0);
        }
        __syncthreads();
    }

    const int which = o0 / 768;
    const float* bias = (which == 0) ? qb : ((which == 1) ? kb : vb);
    ushort_t* dst = qkvb + (size_t)which * QKV_ELEMS;
    const float sc = (which == 0) ? SCALE : 1.0f;

#pragma unroll
    for (int mi = 0; mi < 4; ++mi) {
#pragma unroll
        for (int r = 0; r < 4; ++r) {
            const int m = m0 + wm * 64 + mi * 16 + quad * 4 + r;
            if (m < BN) {
                const int b = m / 197, n = m % 197;
#pragma unroll
                for (int ni = 0; ni < 4; ++ni) {
                    const int o  = o0 + wn * 64 + ni * 16 + li;
                    const int ol = o - which * 768;
                    const int h = ol >> 6, d = ol & 63;
                    dst[(((size_t)b * 12 + h) * 197 + n) * 64 + d] =
                        f2bf((acc[mi][ni][r] + bias[ol]) * sc);
                }
            }
        }
    }
}

// ---------------------------------------------------------------------------
// Kernel 2: fused MFMA attention (R9-proven: single-pass softmax, merged
// QsPs buffer, 5 blocks/CU via 28.7KB LDS, setprio around MFMA clusters).
// (256,5) is safe HERE: peak register need ~100 < the (256,5) cap; verified
// no-spill in R9 at 222.4us.
// ---------------------------------------------------------------------------
__global__ __launch_bounds__(256, 5) void attn_mfma(
    const ushort_t* __restrict__ qkvb,    // Qb,Kb,Vb consecutive, bf16
    const ushort_t* __restrict__ t4,      // [4][12][197][72] bf16
    ushort_t* __restrict__ aout)          // [BN, 768] bf16
{
    __shared__ ushort_t QsPs[64 * STRV];  // Q stage -> bias tile -> Ps
    __shared__ ushort_t Ks[64 * 64];
    __shared__ ushort_t Vt[64 * STRV];

    const int f = xcd_chunk(blockIdx.y * 4 + blockIdx.x, 4 * 768);
    const int rt = f & 3, bh = f >> 2;
    const int h = bh % 12, bb = bh / 12;
    const int t = threadIdx.x;
    const int w = t >> 6, lane = t & 63, quad = lane >> 4, li = lane & 15;
    const size_t base = (size_t)bh * (197 * 64);
    const ushort_t* Qg = qkvb + base;
    const ushort_t* Kg = qkvb + (size_t)QKV_ELEMS + base;
    const ushort_t* Vg = qkvb + (size_t)2 * QKV_ELEMS + base;
    const int r0 = rt * 64;
    const ushort_t* slab = t4 + (size_t)(rt * 12 + h) * (197 * TPAD);

    {
        const int rloc = lane >> 3, g = (lane & 7) ^ rloc;
#pragma unroll
        for (int s = 0; s < 2; ++s) {
            const int rb = (w * 2 + s) * 8;
            gload_lds16(Qg + (size_t)(r0 + rb + rloc) * 64 + g * 8, &QsPs[rb * 64]);
        }
    }

    int nrow[4];
#pragma unroll
    for (int r = 0; r < 4; ++r) nrow[r] = r0 + w * 16 + quad * 4 + r;

    __syncthreads();

    bf16x8 aq0, aq1;
    {
        const int rq = w * 16 + li, rxq = rq & 7;
        aq0 = *(const bf16x8*)&QsPs[rq * 64 + (quad ^ rxq) * 8];
        aq1 = *(const bf16x8*)&QsPs[rq * 64 + ((4 + quad) ^ rxq) * 8];
    }
    // Workgroup barrier: all waves' Q-frag ds_reads retired before any wave
    // DMAs the first bias tile into QsPs (R6's race lesson).
    __syncthreads();

    // ---- Phase 1: QK^T + bias, all score tiles in registers -------------
    floatx4 sv[13];    // idx = cc*4+tl (cc<3) ; 12 = (cc=3, tl=0)
#pragma unroll
    for (int cc = 0; cc < 4; ++cc) {
        {
            const int rloc = lane >> 3, g = (lane & 7) ^ rloc;
#pragma unroll
            for (int s = 0; s < 2; ++s) {
                const int rb = (w * 2 + s) * 8;
                if (cc < 3 || rb < 16)   // cc=3: only K rows 0..15 needed
                    gload_lds16(Kg + (size_t)(cc * 64 + rb + rloc) * 64 + g * 8,
                                &Ks[rb * 64]);
            }
        }
        // bias tile: 9216B contiguous (cc=3: first 3 chunks cover rows 0..21)
        for (int c = w; c < ((cc == 3) ? 3 : 9); c += 4)
            gload_lds16(slab + (size_t)cc * 4608 + c * 512 + lane * 8,
                        &QsPs[c * 512]);
        __syncthreads();

        __builtin_amdgcn_s_setprio(1);
#pragma unroll
        for (int tl = 0; tl < 4; ++tl) {
            if (cc < 3 || tl == 0) {
                const int rk = tl * 16 + li, rxk = rk & 7;
                bf16x8 bk0 = *(const bf16x8*)&Ks[rk * 64 + (quad ^ rxk) * 8];
                bf16x8 bk1 = *(const bf16x8*)&Ks[rk * 64 + ((4 + quad) ^ rxk) * 8];
                floatx4 sa = (floatx4)0.f;
                sa = __builtin_amdgcn_mfma_f32_16x16x32_bf16(aq0, bk0, sa, 0, 0, 0);
                sa = __builtin_amdgcn_mfma_f32_16x16x32_bf16(aq1, bk1, sa, 0, 0, 0);
                const int mg = cc * 64 + tl * 16 + li;
                if (mg >= 197) {
#pragma unroll
                    for (int r = 0; r < 4; ++r) sa[r] = -INFINITY;
                } else {
                    ushort4 bv = *(const ushort4*)
                        &QsPs[(tl * 16 + li) * TPAD + w * 16 + quad * 4];
                    sa[0] += bf2f(bv.x);
                    sa[1] += bf2f(bv.y);
                    sa[2] += bf2f(bv.z);
                    sa[3] += bf2f(bv.w);
                }
                sv[cc * 4 + tl] = sa;    // static index (loops unrolled)
            }
        }
        __builtin_amdgcn_s_setprio(0);
        __syncthreads();
    }

    // ---- Phase 2: single-pass softmax (registers only) ------------------
    float inv[4];
#pragma unroll
    for (int r = 0; r < 4; ++r) {
        float mx = sv[0][r];
#pragma unroll
        for (int i = 1; i < 13; ++i) mx = fmaxf(mx, sv[i][r]);
        mx = fmaxf(mx, __shfl_xor(mx, 1));
        mx = fmaxf(mx, __shfl_xor(mx, 2));
        mx = fmaxf(mx, __shfl_xor(mx, 4));
        mx = fmaxf(mx, __shfl_xor(mx, 8));
        float rs = 0.f;
#pragma unroll
        for (int i = 0; i < 13; ++i) {
            const float p = __expf(sv[i][r] - mx);   // -INF -> 0
            sv[i][r] = p;
            rs += p;
        }
        rs += __shfl_xor(rs, 1);
        rs += __shfl_xor(rs, 2);
        rs += __shfl_xor(rs, 4);
        rs += __shfl_xor(rs, 8);
        inv[r] = 1.0f / rs;
    }

    floatx4 accO[4];
#pragma unroll
    for (int dt = 0; dt < 4; ++dt) accO[dt] = (floatx4)0.f;

    // ---- Phase 3: PV (Ps lives in the QsPs buffer; bias tile is dead) ----
#pragma unroll
    for (int cc = 0; cc < 4; ++cc) {
        {
            const int c = lane;
            const int mg = cc * 64 + c;
            ushort8 v0, v1;
            if (mg < 197) {
                v0 = *(const ushort8*)(Vg + (size_t)mg * 64 + w * 16);
                v1 = *(const ushort8*)(Vg + (size_t)mg * 64 + w * 16 + 8);
            } else {
                v0 = (ushort8)(unsigned short)0; v1 = v0;
            }
#pragma unroll
            for (int j = 0; j < 8; ++j) Vt[(w * 16 + j) * STRV + c] = v0[j];
#pragma unroll
            for (int j = 0; j < 8; ++j) Vt[(w * 16 + 8 + j) * STRV + c] = v1[j];
        }
        // write P tile from registers (cc=3: only tl=0; stale cols x V=0)
#pragma unroll
        for (int r = 0; r < 4; ++r) {
            const int prow = w * 16 + quad * 4 + r;
#pragma unroll
            for (int tl = 0; tl < 4; ++tl)
                if (cc < 3 || tl == 0)
                    QsPs[prow * STRV + tl * 16 + li] = f2bf(sv[cc * 4 + tl][r]);
        }
        __syncthreads();

        {
            const int rp = w * 16 + li;
            bf16x8 pa0 = *(const bf16x8*)&QsPs[rp * STRV + 0  + quad * 8];
            bf16x8 pa1 = *(const bf16x8*)&QsPs[rp * STRV + 32 + quad * 8];
            __builtin_amdgcn_s_setprio(1);
#pragma unroll
            for (int dt = 0; dt < 4; ++dt) {
                const int rv = dt * 16 + li;
                bf16x8 bv0 = *(const bf16x8*)&Vt[rv * STRV + 0  + quad * 8];
                bf16x8 bv1 = *(const bf16x8*)&Vt[rv * STRV + 32 + quad * 8];
                accO[dt] = __builtin_amdgcn_mfma_f32_16x16x32_bf16(
                    pa0, bv0, accO[dt], 0, 0, 0);
                accO[dt] = __builtin_amdgcn_mfma_f32_16x16x32_bf16(
                    pa1, bv1, accO[dt], 0, 0, 0);
            }
            __builtin_amdgcn_s_setprio(0);
        }
        __syncthreads();
    }

#pragma unroll
    for (int r = 0; r < 4; ++r) {
        const int n = nrow[r];
        if (n < 197) {
            ushort_t* op = aout + ((size_t)(bb * 197 + n)) * 768 + h * 64;
#pragma unroll
            for (int dt = 0; dt < 4; ++dt)
                op[dt * 16 + li] = f2bf(accO[dt][r] * inv[r]);
        }
    }
}

// ---------------------------------------------------------------------------
// Kernel 3: output projection GEMM (R0 128^2 core + XCD-chunked remap).
// (256,4): same VGPR-floor rationale as qkv.
// ---------------------------------------------------------------------------
__global__ __launch_bounds__(256, 4) void proj_gemm_mfma(
    const ushort_t* __restrict__ ab,   // [BN_PAD, 768] bf16
    const ushort_t* __restrict__ wb,   // [768, 768] bf16
    const float* __restrict__ bias,    // [768]
    float* __restrict__ out)           // [BN, 768] fp32
{
    __shared__ ushort_t lA[128 * 64];
    __shared__ ushort_t lB[128 * 64];
    const int t = threadIdx.x;
    const int w = t >> 6, lane = t & 63;
    const int quad = lane >> 4, li = lane & 15;
    const int wm = w >> 1, wn = w & 1;
    const int f = xcd_chunk(blockIdx.y * 6 + blockIdx.x, 6 * 99);
    const int o0 = (f % 6) * 128, m0 = (f / 6) * 128;

    floatx4 acc[4][4];
#pragma unroll
    for (int i = 0; i < 4; ++i)
#pragma unroll
        for (int j = 0; j < 4; ++j) acc[i][j] = (floatx4)0.f;

    const int rloc = lane >> 3;
    const int gdma = (lane & 7) ^ rloc;
    const int rx   = li & 7;

    for (int kt = 0; kt < 12; ++kt) {
        const int k0 = kt * 64;
#pragma unroll
        for (int s = 0; s < 4; ++s) {
            const int rb = w * 32 + s * 8;
            gload_lds16(ab + ((size_t)(m0 + rb + rloc)) * 768 + k0 + gdma * 8,
                        &lA[rb * 64]);
            gload_lds16(wb + ((size_t)(o0 + rb + rloc)) * 768 + k0 + gdma * 8,
                        &lB[rb * 64]);
        }
        __syncthreads();
#pragma unroll
        for (int kk = 0; kk < 2; ++kk) {
            bf16x8 af[4], bfr[4];
#pragma unroll
            for (int mi = 0; mi < 4; ++mi)
                af[mi] = *(const bf16x8*)
                    &lA[(wm * 64 + mi * 16 + li) * 64 + ((kk * 4 + quad) ^ rx) * 8];
#pragma unroll
            for (int ni = 0; ni < 4; ++ni)
                bfr[ni] = *(const bf16x8*)
                    &lB[(wn * 64 + ni * 16 + li) * 64 + ((kk * 4 + quad) ^ rx) * 8];
#pragma unroll
            for (int mi = 0; mi < 4; ++mi)
#pragma unroll
                for (int ni = 0; ni < 4; ++ni)
                    acc[mi][ni] = __builtin_amdgcn_mfma_f32_16x16x32_bf16(
                        af[mi], bfr[ni], acc[mi][ni], 0, 0, 0);
        }
        __syncthreads();
    }

#pragma unroll
    for (int mi = 0; mi < 4; ++mi) {
#pragma unroll
        for (int r = 0; r < 4; ++r) {
            const int m = m0 + wm * 64 + mi * 16 + quad * 4 + r;
            if (m < BN) {
                float* op = out + (size_t)m * 768;
#pragma unroll
                for (int ni = 0; ni < 4; ++ni) {
                    const int o = o0 + wn * 64 + ni * 16 + li;
                    op[o] = acc[mi][ni][r] + bias[o];
                }
            }
        }
    }
}

// ---------------------------------------------------------------------------
// ws layout (bytes):
//   [0, 58097664)            qkvb bf16 (3 x B,H,N,D)
//   [58097664, 77561856)     xb bf16 [12672 x 768]; aliased by aout bf16
//   [77561856, 81100800)     wb bf16 [2304 x 768] (live cvt..qkv), THEN
//                            T4 bias table [4][12][197][72] bf16 (1361664B,
//                            built after qkv, read by attn)
//   [81100800, 82280448)     pwb bf16 [768 x 768]
// ---------------------------------------------------------------------------
extern "C" void kernel_launch(void* const* d_in, const int* in_sizes, int n_in,
                              void* d_out, int out_size, void* d_ws, size_t ws_size,
                              hipStream_t stream)
{
    const float* x         = (const float*)d_in[0];
    const float* qkv_w     = (const float*)d_in[1];
    const float* q_bias    = (const float*)d_in[2];
    const float* k_bias    = (const float*)d_in[3];
    const float* v_bias    = (const float*)d_in[4];
    const float* rel_table = (const float*)d_in[5];
    const float* proj_w    = (const float*)d_in[6];
    const float* proj_b    = (const float*)d_in[7];
    float* out = (float*)d_out;

    char* ws = (char*)d_ws;
    ushort_t* qkvb  = (ushort_t*)ws;
    ushort_t* xb    = (ushort_t*)(ws + 58097664);
    ushort_t* aoutb = xb;                      // alias (xb dead after qkv_gemm)
    ushort_t* wb    = (ushort_t*)(ws + 77561856);
    ushort_t* t4b   = wb;                      // alias (wb dead after qkv_gemm)
    ushort_t* pwb   = (ushort_t*)(ws + 81100800);

    // one fused conversion launch: 3010560 float4's exactly = 11760 * 256
    cvt_all<<<11760, 256, 0, stream>>>(x, qkv_w, proj_w, xb, wb, pwb);

    dim3 g1(18, 99);
    qkv_gemm_mfma<<<g1, 256, 0, stream>>>(xb, wb, q_bias, k_bias, v_bias, qkvb);

    // T4 bias table into the now-dead wb region: 56736 threads = 222 * 256
    build_rpb<<<222, 256, 0, stream>>>(rel_table, t4b);

    dim3 g2(4, 768);
    attn_mfma<<<g2, 256, 0, stream>>>(qkvb, t4b, aoutb);

    dim3 g3(6, 99);
    proj_gemm_mfma<<<g3, 256, 0, stream>>>(aoutb, pwb, proj_b, out);
}

// Round 12
// 217.168 us; speedup vs baseline: 1.2965x; 1.0135x over previous
//
#include <hip/hip_runtime.h>
#include <math.h>

#define B_   64
#define N_   197
#define C_   768
#define H_   12
#define D_   64
#define BN   12608      // B_*N_
#define BN_PAD 12672    // 99*128 (GEMM M padded)
#define QKV_ELEMS 9682944   // B_*H_*N_*D_ = BN*C_
#define SCALE 0.125f    // D^-0.5
#define STRV 80         // Vt/Ps LDS row stride (ushorts): 160B, 16B-aligned
#define TPAD 72         // T4 bias row pad (ushorts): 144B rows, 16B-aligned

typedef unsigned short ushort_t;
using bf16x8  = __attribute__((ext_vector_type(8))) __bf16;
using floatx4 = __attribute__((ext_vector_type(4))) float;
using ushort8 = __attribute__((ext_vector_type(8))) unsigned short;

__device__ __forceinline__ ushort_t f2bf(float f) {
    union { float f; unsigned u; } v; v.f = f;
    unsigned r = v.u + 0x7FFF + ((v.u >> 16) & 1);   // RNE
    return (ushort_t)(r >> 16);
}

__device__ __forceinline__ float bf2f(ushort_t u) {
    union { unsigned u; float f; } v; v.u = ((unsigned)u) << 16;
    return v.f;
}

__device__ __forceinline__ void gload_lds16(const void* g, void* l) {
    __builtin_amdgcn_global_load_lds(
        (const __attribute__((address_space(1))) unsigned*)g,
        (__attribute__((address_space(3))) unsigned*)l, 16, 0, 0);
}

// T1: bijective XCD-chunked block remap (m204).
__device__ __forceinline__ int xcd_chunk(int orig, int nwg) {
    const int q = nwg >> 3, r = nwg & 7;
    const int x = orig & 7, i = orig >> 3;
    const int base = (x < r) ? x * (q + 1) : r * (q + 1) + (x - r) * q;
    return base + i;
}

// ---------------------------------------------------------------------------
// fused fp32 -> bf16 conversion for all three tensors (one launch, R4-proven)
// ranges (float4 units): x 2420736 | qkv_w 442368 | proj_w 147456
// total 3010560 = 11760 * 256 exactly.
// ---------------------------------------------------------------------------
__global__ __launch_bounds__(256) void cvt_all(
    const float* __restrict__ x,  const float* __restrict__ w1,
    const float* __restrict__ w2,
    ushort_t* __restrict__ xb, ushort_t* __restrict__ wb,
    ushort_t* __restrict__ pwb)
{
    const int i = blockIdx.x * 256 + threadIdx.x;
    const float* s; ushort_t* d; int j;
    if (i < 2420736)      { s = x;  d = xb;  j = i; }
    else if (i < 2863104) { s = w1; d = wb;  j = i - 2420736; }
    else                  { s = w2; d = pwb; j = i - 2863104; }
    float4 v = ((const float4*)s)[j];
    ushort4 o;
    o.x = f2bf(v.x); o.y = f2bf(v.y); o.z = f2bf(v.z); o.w = f2bf(v.w);
    ((ushort4*)d)[j] = o;
}

// ---------------------------------------------------------------------------
// build_rpb: pregather relative-position bias, TRANSPOSED + rt-partitioned:
//   T4[rt][h][m][n_loc] (bf16), n = rt*64 + n_loc, n_loc in [0,72).
// Row = 72 ushorts = 144B (16B-aligned) so an attn block's per-cc slice
// (m = cc*64..cc*64+63, all n_loc) is ONE contiguous 9216B slab -> staged to
// LDS by 9 global_load_lds calls.  Invalid (n>196) entries = 0 (rows are
// discarded by the attn epilogue).  Lives in the dead wb region (built AFTER
// qkv_gemm).  idx math identical to gen_relative_position_index.
// ---------------------------------------------------------------------------
__global__ __launch_bounds__(256) void build_rpb(
    const float* __restrict__ rel_table,  // [732, 12]
    ushort_t* __restrict__ t4)            // [4][12][197][72] bf16
{
    const int p = blockIdx.x * 256 + threadIdx.x;   // over 4*197*72 = 56736
    if (p >= 4 * 197 * TPAD) return;
    const int nl = p % TPAD;
    const int rest = p / TPAD;
    const int m = rest % 197, rt = rest / 197;
    const int n = rt * 64 + nl;
    const bool valid = (n < 197);
    int idx = 0;
    if (valid) {
        if (n == 0 && m == 0)      idx = 731;
        else if (n == 0)           idx = 729;
        else if (m == 0)           idx = 730;
        else {
            const int pp = n - 1, qq = m - 1;
            idx = (pp / 14 - qq / 14 + 13) * 27 + (pp % 14 - qq % 14 + 13);
        }
    }
#pragma unroll
    for (int h = 0; h < 12; ++h)
        t4[((size_t)(rt * 12 + h) * 197 + m) * TPAD + nl] =
            valid ? f2bf(rel_table[idx * 12 + h]) : (ushort_t)0;
}

// ---------------------------------------------------------------------------
// Kernel 1: QKV projection GEMM (R0 128^2 core + XCD-chunked remap).
// __launch_bounds__(256,4): VGPR cap 128 >= the 64-VGPR accumulator floor.
// R10's (256,5) capped VGPR at 48 -> acc spilled to scratch (WRITE_SIZE
// 56.7->94MB, dur 57->112us).  DO NOT raise the min-waves bound here.
// Epilogue writes bf16 Q(scaled)/K/V in (B,H,N,D).
// ---------------------------------------------------------------------------
__global__ __launch_bounds__(256, 4) void qkv_gemm_mfma(
    const ushort_t* __restrict__ xb,   // [BN_PAD, 768] bf16
    const ushort_t* __restrict__ wb,   // [2304, 768] bf16
    const float* __restrict__ qb,
    const float* __restrict__ kb,
    const float* __restrict__ vb,
    ushort_t* __restrict__ qkvb)       // 3 x [B,H,N,D] bf16
{
    __shared__ ushort_t lA[128 * 64];
    __shared__ ushort_t lB[128 * 64];
    const int t = threadIdx.x;
    const int w = t >> 6, lane = t & 63;
    const int quad = lane >> 4, li = lane & 15;
    const int wm = w >> 1, wn = w & 1;
    const int f = xcd_chunk(blockIdx.y * 18 + blockIdx.x, 18 * 99);
    const int o0 = (f % 18) * 128, m0 = (f / 18) * 128;

    floatx4 acc[4][4];
#pragma unroll
    for (int i = 0; i < 4; ++i)
#pragma unroll
        for (int j = 0; j < 4; ++j) acc[i][j] = (floatx4)0.f;

    const int rloc = lane >> 3;            // row within 8-row DMA chunk
    const int gdma = (lane & 7) ^ rloc;    // swizzled global granule
    const int rx   = li & 7;               // frag-read un-swizzle key

    for (int kt = 0; kt < 12; ++kt) {
        const int k0 = kt * 64;
#pragma unroll
        for (int s = 0; s < 4; ++s) {
            const int rb = w * 32 + s * 8;
            gload_lds16(xb + ((size_t)(m0 + rb + rloc)) * 768 + k0 + gdma * 8,
                        &lA[rb * 64]);
            gload_lds16(wb + ((size_t)(o0 + rb + rloc)) * 768 + k0 + gdma * 8,
                        &lB[rb * 64]);
        }
        __syncthreads();
#pragma unroll
        for (int kk = 0; kk < 2; ++kk) {
            bf16x8 af[4], bfr[4];
#pragma unroll
            for (int mi = 0; mi < 4; ++mi)
                af[mi] = *(const bf16x8*)
                    &lA[(wm * 64 + mi * 16 + li) * 64 + ((kk * 4 + quad) ^ rx) * 8];
#pragma unroll
            for (int ni = 0; ni < 4; ++ni)
                bfr[ni] = *(const bf16x8*)
                    &lB[(wn * 64 + ni * 16 + li) * 64 + ((kk * 4 + quad) ^ rx) * 8];
#pragma unroll
            for (int mi = 0; mi < 4; ++mi)
#pragma unroll
                for (int ni = 0; ni < 4; ++ni)
                    acc[mi][ni] = __builtin_amdgcn_mfma_f32_16x16x32_bf16(
                        af[mi], bfr[ni], acc[mi][ni], 0, 0, 0);
        }
        __syncthreads();
    }

    const int which = o0 / 768;
    const float* bias = (which == 0) ? qb : ((which == 1) ? kb : vb);
    ushort_t* dst = qkvb + (size_t)which * QKV_ELEMS;
    const float sc = (which == 0) ? SCALE : 1.0f;

#pragma unroll
    for (int mi = 0; mi < 4; ++mi) {
#pragma unroll
        for (int r = 0; r < 4; ++r) {
            const int m = m0 + wm * 64 + mi * 16 + quad * 4 + r;
            if (m < BN) {
                const int b = m / 197, n = m % 197;
#pragma unroll
                for (int ni = 0; ni < 4; ++ni) {
                    const int o  = o0 + wn * 64 + ni * 16 + li;
                    const int ol = o - which * 768;
                    const int h = ol >> 6, d = ol & 63;
                    dst[(((size_t)b * 12 + h) * 197 + n) * 64 + d] =
                        f2bf((acc[mi][ni][r] + bias[ol]) * sc);
                }
            }
        }
    }
}

// ---------------------------------------------------------------------------
// Kernel 2: fused MFMA attention (single-pass softmax, merged QsPs buffer,
// setprio).  R12 delta: __launch_bounds__(256,4) — R11 profile showed the
// (256,5) bound capped VGPR at 48 < sv[13]'s 52 -> scratch spill (WRITE_SIZE
// 18.9->34.3MB).  With cap 128 the compiler can keep sv in regs; if actual
// use lands <=102 VGPR the HW still co-schedules 5 blocks/CU (LDS 28.7KB
// allows 5.6) WITHOUT the bound.  Residency comes from actual use, not the
// bound; the bound only squeezes the allocator (R10 lesson).
// ---------------------------------------------------------------------------
__global__ __launch_bounds__(256, 4) void attn_mfma(
    const ushort_t* __restrict__ qkvb,    // Qb,Kb,Vb consecutive, bf16
    const ushort_t* __restrict__ t4,      // [4][12][197][72] bf16
    ushort_t* __restrict__ aout)          // [BN, 768] bf16
{
    __shared__ ushort_t QsPs[64 * STRV];  // Q stage -> bias tile -> Ps
    __shared__ ushort_t Ks[64 * 64];
    __shared__ ushort_t Vt[64 * STRV];

    const int f = xcd_chunk(blockIdx.y * 4 + blockIdx.x, 4 * 768);
    const int rt = f & 3, bh = f >> 2;
    const int h = bh % 12, bb = bh / 12;
    const int t = threadIdx.x;
    const int w = t >> 6, lane = t & 63, quad = lane >> 4, li = lane & 15;
    const size_t base = (size_t)bh * (197 * 64);
    const ushort_t* Qg = qkvb + base;
    const ushort_t* Kg = qkvb + (size_t)QKV_ELEMS + base;
    const ushort_t* Vg = qkvb + (size_t)2 * QKV_ELEMS + base;
    const int r0 = rt * 64;
    const ushort_t* slab = t4 + (size_t)(rt * 12 + h) * (197 * TPAD);

    {
        const int rloc = lane >> 3, g = (lane & 7) ^ rloc;
#pragma unroll
        for (int s = 0; s < 2; ++s) {
            const int rb = (w * 2 + s) * 8;
            gload_lds16(Qg + (size_t)(r0 + rb + rloc) * 64 + g * 8, &QsPs[rb * 64]);
        }
    }

    int nrow[4];
#pragma unroll
    for (int r = 0; r < 4; ++r) nrow[r] = r0 + w * 16 + quad * 4 + r;

    __syncthreads();

    bf16x8 aq0, aq1;
    {
        const int rq = w * 16 + li, rxq = rq & 7;
        aq0 = *(const bf16x8*)&QsPs[rq * 64 + (quad ^ rxq) * 8];
        aq1 = *(const bf16x8*)&QsPs[rq * 64 + ((4 + quad) ^ rxq) * 8];
    }
    // Workgroup barrier: all waves' Q-frag ds_reads retired before any wave
    // DMAs the first bias tile into QsPs (R6's race lesson).
    __syncthreads();

    // ---- Phase 1: QK^T + bias, all score tiles in registers -------------
    floatx4 sv[13];    // idx = cc*4+tl (cc<3) ; 12 = (cc=3, tl=0)
#pragma unroll
    for (int cc = 0; cc < 4; ++cc) {
        {
            const int rloc = lane >> 3, g = (lane & 7) ^ rloc;
#pragma unroll
            for (int s = 0; s < 2; ++s) {
                const int rb = (w * 2 + s) * 8;
                if (cc < 3 || rb < 16)   // cc=3: only K rows 0..15 needed
                    gload_lds16(Kg + (size_t)(cc * 64 + rb + rloc) * 64 + g * 8,
                                &Ks[rb * 64]);
            }
        }
        // bias tile: 9216B contiguous (cc=3: first 3 chunks cover rows 0..21)
        for (int c = w; c < ((cc == 3) ? 3 : 9); c += 4)
            gload_lds16(slab + (size_t)cc * 4608 + c * 512 + lane * 8,
                        &QsPs[c * 512]);
        __syncthreads();

        __builtin_amdgcn_s_setprio(1);
#pragma unroll
        for (int tl = 0; tl < 4; ++tl) {
            if (cc < 3 || tl == 0) {
                const int rk = tl * 16 + li, rxk = rk & 7;
                bf16x8 bk0 = *(const bf16x8*)&Ks[rk * 64 + (quad ^ rxk) * 8];
                bf16x8 bk1 = *(const bf16x8*)&Ks[rk * 64 + ((4 + quad) ^ rxk) * 8];
                floatx4 sa = (floatx4)0.f;
                sa = __builtin_amdgcn_mfma_f32_16x16x32_bf16(aq0, bk0, sa, 0, 0, 0);
                sa = __builtin_amdgcn_mfma_f32_16x16x32_bf16(aq1, bk1, sa, 0, 0, 0);
                const int mg = cc * 64 + tl * 16 + li;
                if (mg >= 197) {
#pragma unroll
                    for (int r = 0; r < 4; ++r) sa[r] = -INFINITY;
                } else {
                    ushort4 bv = *(const ushort4*)
                        &QsPs[(tl * 16 + li) * TPAD + w * 16 + quad * 4];
                    sa[0] += bf2f(bv.x);
                    sa[1] += bf2f(bv.y);
                    sa[2] += bf2f(bv.z);
                    sa[3] += bf2f(bv.w);
                }
                sv[cc * 4 + tl] = sa;    // static index (loops unrolled)
            }
        }
        __builtin_amdgcn_s_setprio(0);
        __syncthreads();
    }

    // ---- Phase 2: single-pass softmax (registers only) ------------------
    float inv[4];
#pragma unroll
    for (int r = 0; r < 4; ++r) {
        float mx = sv[0][r];
#pragma unroll
        for (int i = 1; i < 13; ++i) mx = fmaxf(mx, sv[i][r]);
        mx = fmaxf(mx, __shfl_xor(mx, 1));
        mx = fmaxf(mx, __shfl_xor(mx, 2));
        mx = fmaxf(mx, __shfl_xor(mx, 4));
        mx = fmaxf(mx, __shfl_xor(mx, 8));
        float rs = 0.f;
#pragma unroll
        for (int i = 0; i < 13; ++i) {
            const float p = __expf(sv[i][r] - mx);   // -INF -> 0
            sv[i][r] = p;
            rs += p;
        }
        rs += __shfl_xor(rs, 1);
        rs += __shfl_xor(rs, 2);
        rs += __shfl_xor(rs, 4);
        rs += __shfl_xor(rs, 8);
        inv[r] = 1.0f / rs;
    }

    floatx4 accO[4];
#pragma unroll
    for (int dt = 0; dt < 4; ++dt) accO[dt] = (floatx4)0.f;

    // ---- Phase 3: PV (Ps lives in the QsPs buffer; bias tile is dead) ----
#pragma unroll
    for (int cc = 0; cc < 4; ++cc) {
        {
            const int c = lane;
            const int mg = cc * 64 + c;
            ushort8 v0, v1;
            if (mg < 197) {
                v0 = *(const ushort8*)(Vg + (size_t)mg * 64 + w * 16);
                v1 = *(const ushort8*)(Vg + (size_t)mg * 64 + w * 16 + 8);
            } else {
                v0 = (ushort8)(unsigned short)0; v1 = v0;
            }
#pragma unroll
            for (int j = 0; j < 8; ++j) Vt[(w * 16 + j) * STRV + c] = v0[j];
#pragma unroll
            for (int j = 0; j < 8; ++j) Vt[(w * 16 + 8 + j) * STRV + c] = v1[j];
        }
        // write P tile from registers (cc=3: only tl=0; stale cols x V=0)
#pragma unroll
        for (int r = 0; r < 4; ++r) {
            const int prow = w * 16 + quad * 4 + r;
#pragma unroll
            for (int tl = 0; tl < 4; ++tl)
                if (cc < 3 || tl == 0)
                    QsPs[prow * STRV + tl * 16 + li] = f2bf(sv[cc * 4 + tl][r]);
        }
        __syncthreads();

        {
            const int rp = w * 16 + li;
            bf16x8 pa0 = *(const bf16x8*)&QsPs[rp * STRV + 0  + quad * 8];
            bf16x8 pa1 = *(const bf16x8*)&QsPs[rp * STRV + 32 + quad * 8];
            __builtin_amdgcn_s_setprio(1);
#pragma unroll
            for (int dt = 0; dt < 4; ++dt) {
                const int rv = dt * 16 + li;
                bf16x8 bv0 = *(const bf16x8*)&Vt[rv * STRV + 0  + quad * 8];
                bf16x8 bv1 = *(const bf16x8*)&Vt[rv * STRV + 32 + quad * 8];
                accO[dt] = __builtin_amdgcn_mfma_f32_16x16x32_bf16(
                    pa0, bv0, accO[dt], 0, 0, 0);
                accO[dt] = __builtin_amdgcn_mfma_f32_16x16x32_bf16(
                    pa1, bv1, accO[dt], 0, 0, 0);
            }
            __builtin_amdgcn_s_setprio(0);
        }
        __syncthreads();
    }

#pragma unroll
    for (int r = 0; r < 4; ++r) {
        const int n = nrow[r];
        if (n < 197) {
            ushort_t* op = aout + ((size_t)(bb * 197 + n)) * 768 + h * 64;
#pragma unroll
            for (int dt = 0; dt < 4; ++dt)
                op[dt * 16 + li] = f2bf(accO[dt][r] * inv[r]);
        }
    }
}

// ---------------------------------------------------------------------------
// Kernel 3: output projection GEMM (R0 128^2 core + XCD-chunked remap).
// (256,4): same VGPR-floor rationale as qkv.
// ---------------------------------------------------------------------------
__global__ __launch_bounds__(256, 4) void proj_gemm_mfma(
    const ushort_t* __restrict__ ab,   // [BN_PAD, 768] bf16
    const ushort_t* __restrict__ wb,   // [768, 768] bf16
    const float* __restrict__ bias,    // [768]
    float* __restrict__ out)           // [BN, 768] fp32
{
    __shared__ ushort_t lA[128 * 64];
    __shared__ ushort_t lB[128 * 64];
    const int t = threadIdx.x;
    const int w = t >> 6, lane = t & 63;
    const int quad = lane >> 4, li = lane & 15;
    const int wm = w >> 1, wn = w & 1;
    const int f = xcd_chunk(blockIdx.y * 6 + blockIdx.x, 6 * 99);
    const int o0 = (f % 6) * 128, m0 = (f / 6) * 128;

    floatx4 acc[4][4];
#pragma unroll
    for (int i = 0; i < 4; ++i)
#pragma unroll
        for (int j = 0; j < 4; ++j) acc[i][j] = (floatx4)0.f;

    const int rloc = lane >> 3;
    const int gdma = (lane & 7) ^ rloc;
    const int rx   = li & 7;

    for (int kt = 0; kt < 12; ++kt) {
        const int k0 = kt * 64;
#pragma unroll
        for (int s = 0; s < 4; ++s) {
            const int rb = w * 32 + s * 8;
            gload_lds16(ab + ((size_t)(m0 + rb + rloc)) * 768 + k0 + gdma * 8,
                        &lA[rb * 64]);
            gload_lds16(wb + ((size_t)(o0 + rb + rloc)) * 768 + k0 + gdma * 8,
                        &lB[rb * 64]);
        }
        __syncthreads();
#pragma unroll
        for (int kk = 0; kk < 2; ++kk) {
            bf16x8 af[4], bfr[4];
#pragma unroll
            for (int mi = 0; mi < 4; ++mi)
                af[mi] = *(const bf16x8*)
                    &lA[(wm * 64 + mi * 16 + li) * 64 + ((kk * 4 + quad) ^ rx) * 8];
#pragma unroll
            for (int ni = 0; ni < 4; ++ni)
                bfr[ni] = *(const bf16x8*)
                    &lB[(wn * 64 + ni * 16 + li) * 64 + ((kk * 4 + quad) ^ rx) * 8];
#pragma unroll
            for (int mi = 0; mi < 4; ++mi)
#pragma unroll
                for (int ni = 0; ni < 4; ++ni)
                    acc[mi][ni] = __builtin_amdgcn_mfma_f32_16x16x32_bf16(
                        af[mi], bfr[ni], acc[mi][ni], 0, 0, 0);
        }
        __syncthreads();
    }

#pragma unroll
    for (int mi = 0; mi < 4; ++mi) {
#pragma unroll
        for (int r = 0; r < 4; ++r) {
            const int m = m0 + wm * 64 + mi * 16 + quad * 4 + r;
            if (m < BN) {
                float* op = out + (size_t)m * 768;
#pragma unroll
                for (int ni = 0; ni < 4; ++ni) {
                    const int o = o0 + wn * 64 + ni * 16 + li;
                    op[o] = acc[mi][ni][r] + bias[o];
                }
            }
        }
    }
}

// ---------------------------------------------------------------------------
// ws layout (bytes):
//   [0, 58097664)            qkvb bf16 (3 x B,H,N,D)
//   [58097664, 77561856)     xb bf16 [12672 x 768]; aliased by aout bf16
//   [77561856, 81100800)     wb bf16 [2304 x 768] (live cvt..qkv), THEN
//                            T4 bias table [4][12][197][72] bf16 (1361664B,
//                            built after qkv, read by attn)
//   [81100800, 82280448)     pwb bf16 [768 x 768]
// ---------------------------------------------------------------------------
extern "C" void kernel_launch(void* const* d_in, const int* in_sizes, int n_in,
                              void* d_out, int out_size, void* d_ws, size_t ws_size,
                              hipStream_t stream)
{
    const float* x         = (const float*)d_in[0];
    const float* qkv_w     = (const float*)d_in[1];
    const float* q_bias    = (const float*)d_in[2];
    const float* k_bias    = (const float*)d_in[3];
    const float* v_bias    = (const float*)d_in[4];
    const float* rel_table = (const float*)d_in[5];
    const float* proj_w    = (const float*)d_in[6];
    const float* proj_b    = (const float*)d_in[7];
    float* out = (float*)d_out;

    char* ws = (char*)d_ws;
    ushort_t* qkvb  = (ushort_t*)ws;
    ushort_t* xb    = (ushort_t*)(ws + 58097664);
    ushort_t* aoutb = xb;                      // alias (xb dead after qkv_gemm)
    ushort_t* wb    = (ushort_t*)(ws + 77561856);
    ushort_t* t4b   = wb;                      // alias (wb dead after qkv_gemm)
    ushort_t* pwb   = (ushort_t*)(ws + 81100800);

    // one fused conversion launch: 3010560 float4's exactly = 11760 * 256
    cvt_all<<<11760, 256, 0, stream>>>(x, qkv_w, proj_w, xb, wb, pwb);

    dim3 g1(18, 99);
    qkv_gemm_mfma<<<g1, 256, 0, stream>>>(xb, wb, q_bias, k_bias, v_bias, qkvb);

    // T4 bias table into the now-dead wb region: 56736 threads = 222 * 256
    build_rpb<<<222, 256, 0, stream>>>(rel_table, t4b);

    dim3 g2(4, 768);
    attn_mfma<<<g2, 256, 0, stream>>>(qkvb, t4b, aoutb);

    dim3 g3(6, 99);
    proj_gemm_mfma<<<g3, 256, 0, stream>>>(aoutb, pwb, proj_b, out);
}